// Round 7
// baseline (258.068 us; speedup 1.0000x reference)
//
#include <hip/hip_runtime.h>

#define BN 4
#define CH 128
#define NN 4096
// 1/sqrt(128) * log2(e): Q pre-scaled so softmax uses exp2 directly
#define SCALE_QL2 0.12751744954339238f

typedef __attribute__((ext_vector_type(8))) short s8b;    // 8 x bf16 (4 VGPR)
typedef __attribute__((ext_vector_type(4))) float f32x4;  // MFMA C/D
typedef __attribute__((ext_vector_type(8))) unsigned short us8;
typedef __attribute__((ext_vector_type(4))) unsigned short us4;

#define MFMA16(a, b, c) __builtin_amdgcn_mfma_f32_16x16x32_bf16((a), (b), (c), 0, 0, 0)

#define GLOAD16(gsrc, ldst) __builtin_amdgcn_global_load_lds( \
    (const __attribute__((address_space(1))) unsigned int*)(gsrc), \
    (__attribute__((address_space(3))) unsigned int*)(ldst), 16, 0, 0)

__device__ __forceinline__ unsigned short f2bf(float f) {
  union { float f; unsigned int u; } v; v.f = f;
  unsigned int r = v.u + 0x7fffu + ((v.u >> 16) & 1u);  // RNE
  return (unsigned short)(r >> 16);
}
__device__ __forceinline__ float bf2f(unsigned short h) {
  union { unsigned int u; float f; } v; v.u = (unsigned int)h << 16;
  return v.f;
}

// ---------------------------------------------------------------------------
// qkv_fused: unchanged from round 6 (passing).
// ---------------------------------------------------------------------------
__global__ __launch_bounds__(256, 2) void qkv_fused(
    const float* __restrict__ x,
    const float* __restrict__ wq, const float* __restrict__ bq,
    const float* __restrict__ wk, const float* __restrict__ bk,
    const float* __restrict__ wv, const float* __restrict__ bv,
    unsigned short* __restrict__ Qt, unsigned short* __restrict__ Kt,
    unsigned short* __restrict__ Vn)
{
  __shared__ __align__(16) unsigned short Xh[64 * 128];  // 16KB
  __shared__ __align__(16) unsigned short Xl[64 * 128];  // 16KB

  const int b = blockIdx.y;
  const int n0 = blockIdx.x * 64;
  const int z = blockIdx.z;
  const float* W; const float* bias;
  if (z == 0)      { W = wq; bias = bq; }
  else if (z == 1) { W = wk; bias = bk; }
  else             { W = wv; bias = bv; }
  const float* Xb = x + (size_t)b * CH * NN;

  const int tid = threadIdx.x;
  const int w = tid >> 6, lane = tid & 63, l15 = lane & 15, g = lane >> 4;
  const int ob = w * 32;

#pragma unroll
  for (int it = 0; it < 8; ++it) {
    int idx = it * 256 + tid;
    int c = idx >> 4;
    int n4 = (idx & 15) * 4;
    float4 v = *reinterpret_cast<const float4*>(&Xb[(size_t)c * NN + n0 + n4]);
    float vv[4] = {v.x, v.y, v.z, v.w};
#pragma unroll
    for (int k = 0; k < 4; ++k) {
      int n = n4 + k;
      unsigned short hh = f2bf(vv[k]);
      unsigned short ll = f2bf(vv[k] - bf2f(hh));
      int ad = n * 128 + (c ^ ((n & 7) << 3));
      Xh[ad] = hh;
      Xl[ad] = ll;
    }
  }

  s8b ah[2][4], al[2][4];
#pragma unroll
  for (int m = 0; m < 2; ++m)
#pragma unroll
    for (int kk = 0; kk < 4; ++kk) {
      int o = ob + m * 16 + l15;
      int c = (kk * 4 + g) * 8;
      float4 w0 = *reinterpret_cast<const float4*>(&W[o * CH + c]);
      float4 w1 = *reinterpret_cast<const float4*>(&W[o * CH + c + 4]);
      float wv8[8] = {w0.x, w0.y, w0.z, w0.w, w1.x, w1.y, w1.z, w1.w};
      s8b hh, ll;
#pragma unroll
      for (int t = 0; t < 8; ++t) {
        unsigned short hv = f2bf(wv8[t]);
        hh[t] = (short)hv;
        ll[t] = (short)f2bf(wv8[t] - bf2f(hv));
      }
      ah[m][kk] = hh;
      al[m][kk] = ll;
    }
  __syncthreads();

  f32x4 acc[2][4];
#pragma unroll
  for (int m = 0; m < 2; ++m)
#pragma unroll
    for (int nst = 0; nst < 4; ++nst)
#pragma unroll
      for (int r = 0; r < 4; ++r) acc[m][nst][r] = 0.f;

#pragma unroll
  for (int kk = 0; kk < 4; ++kk)
#pragma unroll
    for (int nst = 0; nst < 4; ++nst) {
      int n = nst * 16 + l15;
      int ck = (kk * 4 + g) ^ (n & 7);
      s8b bh = *reinterpret_cast<const s8b*>(&Xh[n * 128 + ck * 8]);
      s8b bl = *reinterpret_cast<const s8b*>(&Xl[n * 128 + ck * 8]);
#pragma unroll
      for (int m = 0; m < 2; ++m) {
        acc[m][nst] = MFMA16(ah[m][kk], bh, acc[m][nst]);
        acc[m][nst] = MFMA16(ah[m][kk], bl, acc[m][nst]);
        acc[m][nst] = MFMA16(al[m][kk], bh, acc[m][nst]);
      }
    }
  __syncthreads();

  if (z < 2) {
    const float s = (z == 0) ? SCALE_QL2 : 1.f;
#pragma unroll
    for (int m = 0; m < 2; ++m) {
      float4 b4 = *reinterpret_cast<const float4*>(&bias[ob + m * 16 + g * 4]);
      float bb[4] = {b4.x, b4.y, b4.z, b4.w};
#pragma unroll
      for (int nst = 0; nst < 4; ++nst) {
        int n = nst * 16 + l15;
        int slot = w * 8 + m * 4 + g;
        int sl = slot ^ (n & 7);
        us4 pk;
#pragma unroll
        for (int r = 0; r < 4; ++r) pk[r] = f2bf((acc[m][nst][r] + bb[r]) * s);
        *reinterpret_cast<us4*>(&Xh[n * 128 + sl * 4]) = pk;
      }
    }
    __syncthreads();
    unsigned short* T = (z == 0 ? Qt : Kt) + ((size_t)b * NN + n0) * CH;
#pragma unroll
    for (int it = 0; it < 4; ++it) {
      int idx = it * 256 + tid;
      int n = idx >> 4;
      int j = idx & 15;
      int s0 = (2 * j) ^ (n & 7);
      int s1 = (2 * j + 1) ^ (n & 7);
      us4 a4 = *reinterpret_cast<const us4*>(&Xh[n * 128 + s0 * 4]);
      us4 b4 = *reinterpret_cast<const us4*>(&Xh[n * 128 + s1 * 4]);
      us8 o8;
#pragma unroll
      for (int t = 0; t < 4; ++t) { o8[t] = a4[t]; o8[4 + t] = b4[t]; }
      *reinterpret_cast<us8*>(&T[n * CH + j * 8]) = o8;
    }
  } else {
#pragma unroll
    for (int m = 0; m < 2; ++m) {
      float4 b4 = *reinterpret_cast<const float4*>(&bias[ob + m * 16 + g * 4]);
      float bb[4] = {b4.x, b4.y, b4.z, b4.w};
#pragma unroll
      for (int nst = 0; nst < 4; ++nst) {
        int n = nst * 16 + l15;
#pragma unroll
        for (int r = 0; r < 4; ++r) {
          int o = ob + m * 16 + g * 4 + r;
          Xh[o * 64 + (n ^ ((o & 7) << 3))] = f2bf(acc[m][nst][r] + bb[r]);
        }
      }
    }
    __syncthreads();
    unsigned short* V = Vn + (size_t)b * CH * NN;
#pragma unroll
    for (int it = 0; it < 4; ++it) {
      int idx = it * 256 + tid;
      int o = idx >> 3;
      int j8 = idx & 7;
      us8 v8 = *reinterpret_cast<const us8*>(&Xh[o * 64 + ((j8 ^ (o & 7)) << 3)]);
      *reinterpret_cast<us8*>(&V[(size_t)o * NN + n0 + j8 * 8]) = v8;
    }
  }
}

// ---------------------------------------------------------------------------
// Flash attention v5: NO LDS staging, NO in-loop barriers.
// K/V are L2-resident (2MB/batch vs 4MB/XCD); each wave loads its fragments
// directly global->reg (fully coalesced per instruction). 256 thr = 4 waves
// = 4 key-teams; wave w does 32 tiles of 32 keys at key0=(t*4+w)*32.
// P wave-private in LDS, double-buffered by t&1. One merge at the end.
// LDS 19KB, VGPR<=170 (3 waves/SIMD -> 12 waves/CU, independent waves).
// ---------------------------------------------------------------------------
__global__ __launch_bounds__(256, 3) void flash_attn_v5(
    const unsigned short* __restrict__ Qt,
    const unsigned short* __restrict__ Kt,
    const unsigned short* __restrict__ Vn,
    unsigned short* __restrict__ Oth, unsigned short* __restrict__ Otl)
{
  // loop phase: P = [4 waves][2 buf][32][32] bf16 = 16KB at offset 0
  // epilogue (after sync, overlaid): Mb@0 Lb@512 Db@1024, Obuf@2048 (32x132 f32)
  __shared__ __align__(16) unsigned char smem[18944];

  const int flat = blockIdx.y * 128 + blockIdx.x;
  const int swz = (flat & 7) * 64 + (flat >> 3);  // XCD-aware, bijective (512%8==0)
  const int b = swz >> 7;
  const int n0 = (swz & 127) * 32;

  const int tid = threadIdx.x;
  const int w = tid >> 6, lane = tid & 63, l15 = lane & 15, g = lane >> 4;

  const unsigned short* Qb = Qt + (size_t)b * NN * CH;
  const unsigned short* Kb = Kt + (size_t)b * NN * CH;
  const unsigned short* Vb = Vn + (size_t)b * CH * NN;

  // Q fragments: rows n0 + m*16 + l15, k-chunk (kk*4+g)*8
  s8b qf[2][4];
#pragma unroll
  for (int m = 0; m < 2; ++m)
#pragma unroll
    for (int kk = 0; kk < 4; ++kk) {
      int row = n0 + m * 16 + l15;
      int c = (kk * 4 + g) * 8;
      qf[m][kk] = *reinterpret_cast<const s8b*>(&Qb[(size_t)row * CH + c]);
    }

  f32x4 facc[2][8];
#pragma unroll
  for (int m = 0; m < 2; ++m)
#pragma unroll
    for (int cst = 0; cst < 8; ++cst)
#pragma unroll
      for (int r = 0; r < 4; ++r) facc[m][cst][r] = 0.f;
  float m_run[2][4], l_run[2][4];
#pragma unroll
  for (int m = 0; m < 2; ++m)
#pragma unroll
    for (int r = 0; r < 4; ++r) { m_run[m][r] = -1e30f; l_run[m][r] = 0.f; }

  for (int t = 0; t < 32; ++t) {
    const int key0 = (t * 4 + w) * 32;
    unsigned short* Pt = (unsigned short*)smem + w * 2048 + (t & 1) * 1024;

    // ---- K fragments direct from global (L2-hot), coalesced 16B/lane ----
    s8b kf[2][4];
#pragma unroll
    for (int st = 0; st < 2; ++st)
#pragma unroll
      for (int kk = 0; kk < 4; ++kk)
        kf[st][kk] = *reinterpret_cast<const s8b*>(
            &Kb[(size_t)(key0 + st * 16 + l15) * CH + (kk * 4 + g) * 8]);

    // ---- QK^T: 32 rows x 32 keys ----
    f32x4 sacc[2][2];
#pragma unroll
    for (int m = 0; m < 2; ++m)
#pragma unroll
      for (int st = 0; st < 2; ++st)
#pragma unroll
        for (int r = 0; r < 4; ++r) sacc[m][st][r] = 0.f;
    __builtin_amdgcn_s_setprio(1);
#pragma unroll
    for (int kk = 0; kk < 4; ++kk)
#pragma unroll
      for (int st = 0; st < 2; ++st) {
        sacc[0][st] = MFMA16(qf[0][kk], kf[st][kk], sacc[0][st]);
        sacc[1][st] = MFMA16(qf[1][kk], kf[st][kk], sacc[1][st]);
      }
    __builtin_amdgcn_s_setprio(0);

    // ---- softmax: defer-max + per-lane partial sums (log2 domain) ----
#pragma unroll
    for (int m = 0; m < 2; ++m)
#pragma unroll
      for (int r = 0; r < 4; ++r) {
        float s0 = sacc[m][0][r], s1 = sacc[m][1][r];
        float mt = fmaxf(s0, s1);
        mt = fmaxf(mt, __shfl_xor(mt, 1));
        mt = fmaxf(mt, __shfl_xor(mt, 2));
        mt = fmaxf(mt, __shfl_xor(mt, 4));
        mt = fmaxf(mt, __shfl_xor(mt, 8));
        if (__any(mt > m_run[m][r] + 8.f)) {  // rare after first tile
          float mn = fmaxf(m_run[m][r], mt);
          float f = exp2f(m_run[m][r] - mn);
          l_run[m][r] *= f;
#pragma unroll
          for (int cst = 0; cst < 8; ++cst) facc[m][cst][r] *= f;
          m_run[m][r] = mn;
        }
        float p0 = exp2f(s0 - m_run[m][r]);   // bounded by 2^8
        float p1 = exp2f(s1 - m_run[m][r]);
        l_run[m][r] += p0 + p1;               // per-lane partial
        int rw = m * 16 + g * 4 + r;
        int sch0 = (l15 >> 3) ^ g;
        int sch1 = (2 + (l15 >> 3)) ^ g;
        Pt[rw * 32 + sch0 * 8 + (l15 & 7)] = f2bf(p0);
        Pt[rw * 32 + sch1 * 8 + (l15 & 7)] = f2bf(p1);
      }

    // ---- PV: facc += P . V  (V direct from global, coalesced) ----
    s8b pa[2];
#pragma unroll
    for (int m = 0; m < 2; ++m) {
      int row = m * 16 + l15;
      int sch = g ^ (l15 >> 2);
      pa[m] = *reinterpret_cast<const s8b*>(&Pt[row * 32 + sch * 8]);
    }
    __builtin_amdgcn_s_setprio(1);
#pragma unroll
    for (int cst = 0; cst < 8; ++cst) {
      int c = cst * 16 + l15;
      s8b vf = *reinterpret_cast<const s8b*>(&Vb[(size_t)c * NN + key0 + g * 8]);
      facc[0][cst] = MFMA16(pa[0], vf, facc[0][cst]);
      facc[1][cst] = MFMA16(pa[1], vf, facc[1][cst]);
    }
    __builtin_amdgcn_s_setprio(0);
  }

  // ---- epilogue: reduce deferred sums, merge 4 key-teams, store hi/lo ----
  float l_red[2][4];
#pragma unroll
  for (int m = 0; m < 2; ++m)
#pragma unroll
    for (int r = 0; r < 4; ++r) {
      float rs = l_run[m][r];
      rs += __shfl_xor(rs, 1);
      rs += __shfl_xor(rs, 2);
      rs += __shfl_xor(rs, 4);
      rs += __shfl_xor(rs, 8);
      l_red[m][r] = rs;
    }
  __syncthreads();  // all waves done with their P before overlay

  float* Mb = (float*)smem;            // [4][32]
  float* Lb = (float*)(smem + 512);    // [4][32]
  float* Db = (float*)(smem + 1024);   // [32]
  float* Obuf = (float*)(smem + 2048); // [32][132]

  if (l15 == 0) {
#pragma unroll
    for (int m = 0; m < 2; ++m)
#pragma unroll
      for (int r = 0; r < 4; ++r) {
        int ra = m * 16 + g * 4 + r;
        Mb[w * 32 + ra] = m_run[m][r];
        Lb[w * 32 + ra] = l_red[m][r];
      }
  }
  __syncthreads();
  float fsc[2][4];
#pragma unroll
  for (int m = 0; m < 2; ++m)
#pragma unroll
    for (int r = 0; r < 4; ++r) {
      int ra = m * 16 + g * 4 + r;
      float M = fmaxf(fmaxf(Mb[ra], Mb[32 + ra]), fmaxf(Mb[64 + ra], Mb[96 + ra]));
      fsc[m][r] = exp2f(m_run[m][r] - M);
      if (w == 0 && l15 == 0) {
        float den = Lb[ra] * exp2f(Mb[ra] - M) + Lb[32 + ra] * exp2f(Mb[32 + ra] - M) +
                    Lb[64 + ra] * exp2f(Mb[64 + ra] - M) +
                    Lb[96 + ra] * exp2f(Mb[96 + ra] - M);
        Db[ra] = 1.f / den;
      }
    }
#pragma unroll
  for (int t = 0; t < 4; ++t) {
    __syncthreads();
    if (w == t) {
#pragma unroll
      for (int m = 0; m < 2; ++m)
#pragma unroll
        for (int cst = 0; cst < 8; ++cst)
#pragma unroll
          for (int r = 0; r < 4; ++r) {
            int ra = m * 16 + g * 4 + r;
            int c = cst * 16 + l15;
            float v = facc[m][cst][r] * fsc[m][r];
            if (t == 0) Obuf[ra * 132 + c] = v;
            else        Obuf[ra * 132 + c] += v;
          }
    }
  }
  __syncthreads();
#pragma unroll
  for (int it = 0; it < 2; ++it) {
    int idx = it * 256 + tid;  // 512 = 32 rows x 16 chunks
    int row = idx >> 4;
    int j = idx & 15;
    float inv = Db[row];
    float4 v0 = *reinterpret_cast<const float4*>(&Obuf[row * 132 + j * 8]);
    float4 v1 = *reinterpret_cast<const float4*>(&Obuf[row * 132 + j * 8 + 4]);
    float vv[8] = {v0.x, v0.y, v0.z, v0.w, v1.x, v1.y, v1.z, v1.w};
    us8 hh, ll;
#pragma unroll
    for (int t = 0; t < 8; ++t) {
      float v = vv[t] * inv;
      unsigned short hv = f2bf(v);
      hh[t] = hv;
      ll[t] = f2bf(v - bf2f(hv));
    }
    size_t go = ((size_t)b * NN + n0 + row) * CH + j * 8;
    *reinterpret_cast<us8*>(&Oth[go]) = hh;
    *reinterpret_cast<us8*>(&Otl[go]) = ll;
  }
}

// ---------------------------------------------------------------------------
// out_mfma: unchanged from round 6 (passing).
// ---------------------------------------------------------------------------
__global__ __launch_bounds__(256, 2) void out_mfma(
    const unsigned short* __restrict__ Oth, const unsigned short* __restrict__ Otl,
    const float* __restrict__ wo, const float* __restrict__ bo,
    const float* __restrict__ x, const float* __restrict__ gamma,
    float* __restrict__ y)
{
  __shared__ __align__(16) unsigned char smem[67584];
  unsigned short* Oh = (unsigned short*)smem;
  unsigned short* Ol = (unsigned short*)(smem + 16384);
  float* Obuf = (float*)(smem + 32768);

  const int b = blockIdx.y;
  const int n0 = blockIdx.x * 64;
  const int tid = threadIdx.x;
  const int w = tid >> 6, lane = tid & 63, l15 = lane & 15, g = lane >> 4;
  const int ob = w * 32;

  const unsigned short* OhB = Oth + ((size_t)b * NN + n0) * CH;
  const unsigned short* OlB = Otl + ((size_t)b * NN + n0) * CH;
#pragma unroll
  for (int i = 0; i < 4; ++i) {
    int base = i * 4096 + w * 1024;
    int loff = base + lane * 16;
    int row = loff >> 8;
    int chunk = (loff >> 4) & 15;
    int sk = chunk ^ (row & 7);
    GLOAD16(OhB + (size_t)row * CH + sk * 8, smem + base);
    GLOAD16(OlB + (size_t)row * CH + sk * 8, smem + 16384 + base);
  }

  s8b ah[2][4], al[2][4];
#pragma unroll
  for (int m = 0; m < 2; ++m)
#pragma unroll
    for (int kk = 0; kk < 4; ++kk) {
      int o = ob + m * 16 + l15;
      int c = (kk * 4 + g) * 8;
      float4 w0 = *reinterpret_cast<const float4*>(&wo[o * CH + c]);
      float4 w1 = *reinterpret_cast<const float4*>(&wo[o * CH + c + 4]);
      float wv8[8] = {w0.x, w0.y, w0.z, w0.w, w1.x, w1.y, w1.z, w1.w};
      s8b hh, ll;
#pragma unroll
      for (int t = 0; t < 8; ++t) {
        unsigned short hv = f2bf(wv8[t]);
        hh[t] = (short)hv;
        ll[t] = (short)f2bf(wv8[t] - bf2f(hv));
      }
      ah[m][kk] = hh;
      al[m][kk] = ll;
    }
  const float gm = gamma[0];
  __syncthreads();

  f32x4 acc[2][4];
#pragma unroll
  for (int m = 0; m < 2; ++m)
#pragma unroll
    for (int nst = 0; nst < 4; ++nst)
#pragma unroll
      for (int r = 0; r < 4; ++r) acc[m][nst][r] = 0.f;

#pragma unroll
  for (int kk = 0; kk < 4; ++kk)
#pragma unroll
    for (int nst = 0; nst < 4; ++nst) {
      int n = nst * 16 + l15;
      int ck = (kk * 4 + g) ^ (n & 7);
      s8b bh = *reinterpret_cast<const s8b*>(&Oh[n * 128 + ck * 8]);
      s8b bl = *reinterpret_cast<const s8b*>(&Ol[n * 128 + ck * 8]);
#pragma unroll
      for (int m = 0; m < 2; ++m) {
        acc[m][nst] = MFMA16(ah[m][kk], bh, acc[m][nst]);
        acc[m][nst] = MFMA16(ah[m][kk], bl, acc[m][nst]);
        acc[m][nst] = MFMA16(al[m][kk], bh, acc[m][nst]);
      }
    }
  __syncthreads();

#pragma unroll
  for (int m = 0; m < 2; ++m) {
    float4 b4 = *reinterpret_cast<const float4*>(&bo[ob + m * 16 + g * 4]);
    float bb[4] = {b4.x, b4.y, b4.z, b4.w};
#pragma unroll
    for (int nst = 0; nst < 4; ++nst) {
      int n = nst * 16 + l15;
#pragma unroll
      for (int r = 0; r < 4; ++r) {
        int o = ob + m * 16 + g * 4 + r;
        Obuf[o * 68 + n] = gm * (acc[m][nst][r] + bb[r]);
      }
    }
  }
  __syncthreads();
  const float* Xb = x + (size_t)b * CH * NN;
  float* Yb = y + (size_t)b * CH * NN;
#pragma unroll
  for (int it = 0; it < 8; ++it) {
    int idx = it * 256 + tid;
    int o = idx >> 4;
    int n4 = (idx & 15) * 4;
    float4 v = *reinterpret_cast<const float4*>(&Obuf[o * 68 + n4]);
    float4 rx = *reinterpret_cast<const float4*>(&Xb[(size_t)o * NN + n0 + n4]);
    v.x += rx.x; v.y += rx.y; v.z += rx.z; v.w += rx.w;
    *reinterpret_cast<float4*>(&Yb[(size_t)o * NN + n0 + n4]) = v;
  }
}

// ---------------------------------------------------------------------------
extern "C" void kernel_launch(void* const* d_in, const int* in_sizes, int n_in,
                              void* d_out, int out_size, void* d_ws, size_t ws_size,
                              hipStream_t stream) {
  const float* x     = (const float*)d_in[0];
  const float* wq    = (const float*)d_in[1];
  const float* bq    = (const float*)d_in[2];
  const float* wk    = (const float*)d_in[3];
  const float* bk    = (const float*)d_in[4];
  const float* wv    = (const float*)d_in[5];
  const float* bv    = (const float*)d_in[6];
  const float* wo    = (const float*)d_in[7];
  const float* bo    = (const float*)d_in[8];
  const float* gamma = (const float*)d_in[9];
  float* y = (float*)d_out;

  const size_t per = (size_t)BN * NN * CH;  // 2M bf16 elems = 4MB
  unsigned short* Qt  = (unsigned short*)d_ws;  // [B][N][C] (pre-scaled, log2 dom)
  unsigned short* Kt  = Qt + per;               // [B][N][C]
  unsigned short* Vn  = Kt + per;               // [B][C][N]
  unsigned short* Oth = Vn + per;               // [B][N][C] hi
  unsigned short* Otl = Oth + per;              // [B][N][C] lo

  qkv_fused<<<dim3(NN / 64, BN, 3), 256, 0, stream>>>(x, wq, bq, wk, bk, wv, bv,
                                                      Qt, Kt, Vn);
  flash_attn_v5<<<dim3(NN / 32, BN), 256, 0, stream>>>(Qt, Kt, Vn, Oth, Otl);
  out_mfma<<<dim3(NN / 64, BN), 256, 0, stream>>>(Oth, Otl, wo, bo, x, gamma, y);
}

// Round 8
// 168.125 us; speedup vs baseline: 1.5350x; 1.5350x over previous
//
#include <hip/hip_runtime.h>

#define BN 4
#define CH 128
#define NN 4096
// 1/sqrt(128) * log2(e): Q pre-scaled so softmax uses exp2 directly
#define SCALE_QL2 0.12751744954339238f

typedef __attribute__((ext_vector_type(8))) short s8b;    // 8 x bf16 (4 VGPR)
typedef __attribute__((ext_vector_type(4))) float f32x4;  // MFMA C/D
typedef __attribute__((ext_vector_type(8))) unsigned short us8;
typedef __attribute__((ext_vector_type(4))) unsigned short us4;
typedef __attribute__((ext_vector_type(2))) unsigned int u32x2;

#define MFMA16(a, b, c) __builtin_amdgcn_mfma_f32_16x16x32_bf16((a), (b), (c), 0, 0, 0)

#define GLOAD16(gsrc, ldst) __builtin_amdgcn_global_load_lds( \
    (const __attribute__((address_space(1))) unsigned int*)(gsrc), \
    (__attribute__((address_space(3))) unsigned int*)(ldst), 16, 0, 0)

__device__ __forceinline__ unsigned short f2bf(float f) {
  union { float f; unsigned int u; } v; v.f = f;
  unsigned int r = v.u + 0x7fffu + ((v.u >> 16) & 1u);  // RNE
  return (unsigned short)(r >> 16);
}
__device__ __forceinline__ float bf2f(unsigned short h) {
  union { unsigned int u; float f; } v; v.u = (unsigned int)h << 16;
  return v.f;
}
// raw v_exp_f32 (2^x), no libm edge handling
__device__ __forceinline__ float fexp2(float x) {
  float r;
  asm("v_exp_f32 %0, %1" : "=v"(r) : "v"(x));
  return r;
}
// pack 2 fp32 -> 2 bf16 in one u32 (lo = a, hi = b), RNE
__device__ __forceinline__ unsigned int pk2(float a, float b) {
  unsigned int r;
  asm("v_cvt_pk_bf16_f32 %0, %1, %2" : "=v"(r) : "v"(a), "v"(b));
  return r;
}

// ---------------------------------------------------------------------------
// qkv_fused: unchanged from round 6 (passing).
// ---------------------------------------------------------------------------
__global__ __launch_bounds__(256, 2) void qkv_fused(
    const float* __restrict__ x,
    const float* __restrict__ wq, const float* __restrict__ bq,
    const float* __restrict__ wk, const float* __restrict__ bk,
    const float* __restrict__ wv, const float* __restrict__ bv,
    unsigned short* __restrict__ Qt, unsigned short* __restrict__ Kt,
    unsigned short* __restrict__ Vn)
{
  __shared__ __align__(16) unsigned short Xh[64 * 128];  // 16KB
  __shared__ __align__(16) unsigned short Xl[64 * 128];  // 16KB

  const int b = blockIdx.y;
  const int n0 = blockIdx.x * 64;
  const int z = blockIdx.z;
  const float* W; const float* bias;
  if (z == 0)      { W = wq; bias = bq; }
  else if (z == 1) { W = wk; bias = bk; }
  else             { W = wv; bias = bv; }
  const float* Xb = x + (size_t)b * CH * NN;

  const int tid = threadIdx.x;
  const int w = tid >> 6, lane = tid & 63, l15 = lane & 15, g = lane >> 4;
  const int ob = w * 32;

#pragma unroll
  for (int it = 0; it < 8; ++it) {
    int idx = it * 256 + tid;
    int c = idx >> 4;
    int n4 = (idx & 15) * 4;
    float4 v = *reinterpret_cast<const float4*>(&Xb[(size_t)c * NN + n0 + n4]);
    float vv[4] = {v.x, v.y, v.z, v.w};
#pragma unroll
    for (int k = 0; k < 4; ++k) {
      int n = n4 + k;
      unsigned short hh = f2bf(vv[k]);
      unsigned short ll = f2bf(vv[k] - bf2f(hh));
      int ad = n * 128 + (c ^ ((n & 7) << 3));
      Xh[ad] = hh;
      Xl[ad] = ll;
    }
  }

  s8b ah[2][4], al[2][4];
#pragma unroll
  for (int m = 0; m < 2; ++m)
#pragma unroll
    for (int kk = 0; kk < 4; ++kk) {
      int o = ob + m * 16 + l15;
      int c = (kk * 4 + g) * 8;
      float4 w0 = *reinterpret_cast<const float4*>(&W[o * CH + c]);
      float4 w1 = *reinterpret_cast<const float4*>(&W[o * CH + c + 4]);
      float wv8[8] = {w0.x, w0.y, w0.z, w0.w, w1.x, w1.y, w1.z, w1.w};
      s8b hh, ll;
#pragma unroll
      for (int t = 0; t < 8; ++t) {
        unsigned short hv = f2bf(wv8[t]);
        hh[t] = (short)hv;
        ll[t] = (short)f2bf(wv8[t] - bf2f(hv));
      }
      ah[m][kk] = hh;
      al[m][kk] = ll;
    }
  __syncthreads();

  f32x4 acc[2][4];
#pragma unroll
  for (int m = 0; m < 2; ++m)
#pragma unroll
    for (int nst = 0; nst < 4; ++nst)
#pragma unroll
      for (int r = 0; r < 4; ++r) acc[m][nst][r] = 0.f;

#pragma unroll
  for (int kk = 0; kk < 4; ++kk)
#pragma unroll
    for (int nst = 0; nst < 4; ++nst) {
      int n = nst * 16 + l15;
      int ck = (kk * 4 + g) ^ (n & 7);
      s8b bh = *reinterpret_cast<const s8b*>(&Xh[n * 128 + ck * 8]);
      s8b bl = *reinterpret_cast<const s8b*>(&Xl[n * 128 + ck * 8]);
#pragma unroll
      for (int m = 0; m < 2; ++m) {
        acc[m][nst] = MFMA16(ah[m][kk], bh, acc[m][nst]);
        acc[m][nst] = MFMA16(ah[m][kk], bl, acc[m][nst]);
        acc[m][nst] = MFMA16(al[m][kk], bh, acc[m][nst]);
      }
    }
  __syncthreads();

  if (z < 2) {
    const float s = (z == 0) ? SCALE_QL2 : 1.f;
#pragma unroll
    for (int m = 0; m < 2; ++m) {
      float4 b4 = *reinterpret_cast<const float4*>(&bias[ob + m * 16 + g * 4]);
      float bb[4] = {b4.x, b4.y, b4.z, b4.w};
#pragma unroll
      for (int nst = 0; nst < 4; ++nst) {
        int n = nst * 16 + l15;
        int slot = w * 8 + m * 4 + g;
        int sl = slot ^ (n & 7);
        us4 pk;
#pragma unroll
        for (int r = 0; r < 4; ++r) pk[r] = f2bf((acc[m][nst][r] + bb[r]) * s);
        *reinterpret_cast<us4*>(&Xh[n * 128 + sl * 4]) = pk;
      }
    }
    __syncthreads();
    unsigned short* T = (z == 0 ? Qt : Kt) + ((size_t)b * NN + n0) * CH;
#pragma unroll
    for (int it = 0; it < 4; ++it) {
      int idx = it * 256 + tid;
      int n = idx >> 4;
      int j = idx & 15;
      int s0 = (2 * j) ^ (n & 7);
      int s1 = (2 * j + 1) ^ (n & 7);
      us4 a4 = *reinterpret_cast<const us4*>(&Xh[n * 128 + s0 * 4]);
      us4 b4 = *reinterpret_cast<const us4*>(&Xh[n * 128 + s1 * 4]);
      us8 o8;
#pragma unroll
      for (int t = 0; t < 4; ++t) { o8[t] = a4[t]; o8[4 + t] = b4[t]; }
      *reinterpret_cast<us8*>(&T[n * CH + j * 8]) = o8;
    }
  } else {
#pragma unroll
    for (int m = 0; m < 2; ++m) {
      float4 b4 = *reinterpret_cast<const float4*>(&bias[ob + m * 16 + g * 4]);
      float bb[4] = {b4.x, b4.y, b4.z, b4.w};
#pragma unroll
      for (int nst = 0; nst < 4; ++nst) {
        int n = nst * 16 + l15;
#pragma unroll
        for (int r = 0; r < 4; ++r) {
          int o = ob + m * 16 + g * 4 + r;
          Xh[o * 64 + (n ^ ((o & 7) << 3))] = f2bf(acc[m][nst][r] + bb[r]);
        }
      }
    }
    __syncthreads();
    unsigned short* V = Vn + (size_t)b * CH * NN;
#pragma unroll
    for (int it = 0; it < 4; ++it) {
      int idx = it * 256 + tid;
      int o = idx >> 3;
      int j8 = idx & 7;
      us8 v8 = *reinterpret_cast<const us8*>(&Xh[o * 64 + ((j8 ^ (o & 7)) << 3)]);
      *reinterpret_cast<us8*>(&V[(size_t)o * NN + n0 + j8 * 8]) = v8;
    }
  }
}

// ---------------------------------------------------------------------------
// Flash attention v6: swapped-operand MFMA -> lane-local softmax.
// 512 thr = 8 waves = 2 row-halves x 4 key-teams. QB=64, KB=128 staged
// (single-buffer, swizzled gload_lds — byte-identical to v2/v4 staging).
// QK^T = mfma(K, Q): D[key][q], q = lane&15 -> row-max is 7 in-lane fmax +
// 2 shuffles. PV = mfma(V, P): D[c][q], q = lane&15 (matches softmax state).
// P: 4 cvt_pk + 2 ds_write_b64 per qh, pair-XOR swizzle; PV reads b128.
// exp via raw v_exp_f32. LDS 80KB = Ks 32K | Vs 32K | P 8x2K. grid 256.
// ---------------------------------------------------------------------------
__global__ __launch_bounds__(512, 2) void flash_attn_v6(
    const unsigned short* __restrict__ Qt,
    const unsigned short* __restrict__ Kt,
    const unsigned short* __restrict__ Vn,
    unsigned short* __restrict__ Oth, unsigned short* __restrict__ Otl)
{
  __shared__ __align__(16) unsigned char smem[81920];

  const int flat = blockIdx.y * 64 + blockIdx.x;
  const int swz = (flat & 7) * 32 + (flat >> 3);  // XCD-aware, bijective
  const int b = swz >> 6;
  const int n0 = (swz & 63) * 64;

  const int tid = threadIdx.x;
  const int w = tid >> 6, lane = tid & 63, l15 = lane & 15, g = lane >> 4;
  const int rhalf = w & 1;  // query-row half (32 rows)
  const int h = w >> 1;     // key quarter (32 keys of the 128-tile)

  const unsigned short* Qb = Qt + (size_t)b * NN * CH;
  const unsigned short* Kb = Kt + (size_t)b * NN * CH;
  const unsigned short* Vb = Vn + (size_t)b * CH * NN;

  const unsigned short* Ks = (const unsigned short*)smem;            // [128k][128c]
  const unsigned short* Vs = (const unsigned short*)(smem + 32768);  // [128c][128k]
  unsigned short* Pw = (unsigned short*)(smem + 65536) + w * 1024;   // [2qh][16q][32k]

  // Q fragments (B-operand: col = q = l15)
  s8b qf[2][4];
#pragma unroll
  for (int qh = 0; qh < 2; ++qh)
#pragma unroll
    for (int kk = 0; kk < 4; ++kk) {
      int row = n0 + rhalf * 32 + qh * 16 + l15;
      int c = (kk * 4 + g) * 8;
      qf[qh][kk] = *reinterpret_cast<const s8b*>(&Qb[(size_t)row * CH + c]);
    }

  f32x4 facc[2][8];
#pragma unroll
  for (int qh = 0; qh < 2; ++qh)
#pragma unroll
    for (int cst = 0; cst < 8; ++cst)
#pragma unroll
      for (int r = 0; r < 4; ++r) facc[qh][cst][r] = 0.f;
  float m_run[2] = {-1e30f, -1e30f};
  float l_run[2] = {0.f, 0.f};

  const int x2 = (l15 & 3) << 1;        // P-store granule XOR (keeps bit0)
  const int ppx = g ^ (l15 & 3);        // P-read pair index

  for (int kt = 0; kt < 32; ++kt) {
    const int m0 = kt * 128;
    __syncthreads();  // all reads of previous tile complete
#pragma unroll
    for (int i = 0; i < 4; ++i) {
      int base = i * 8192 + w * 1024;
      int loff = base + lane * 16;
      int row = loff >> 8;
      int chunk = (loff >> 4) & 15;
      int sk = chunk ^ (row & 7);
      GLOAD16(Kb + (size_t)(m0 + row) * CH + sk * 8, smem + base);
      GLOAD16(Vb + (size_t)row * NN + m0 + sk * 8, smem + 32768 + base);
    }
    __syncthreads();  // vmcnt drained: tiles ready

    // ---- QK^T swapped: sacc[qh][st] = K(A) x Q(B) -> D[key][q=l15] ----
    f32x4 sacc[2][2];
#pragma unroll
    for (int qh = 0; qh < 2; ++qh)
#pragma unroll
      for (int st = 0; st < 2; ++st)
#pragma unroll
        for (int r = 0; r < 4; ++r) sacc[qh][st][r] = 0.f;
    __builtin_amdgcn_s_setprio(1);
#pragma unroll
    for (int kk = 0; kk < 4; ++kk)
#pragma unroll
      for (int st = 0; st < 2; ++st) {
        int key = h * 32 + st * 16 + l15;
        int ck = (kk * 4 + g) ^ (key & 7);
        s8b kf = *reinterpret_cast<const s8b*>(&Ks[key * 128 + ck * 8]);
        sacc[0][st] = MFMA16(kf, qf[0][kk], sacc[0][st]);
        sacc[1][st] = MFMA16(kf, qf[1][kk], sacc[1][st]);
      }
    __builtin_amdgcn_s_setprio(0);
    // lane holds scores for q = l15 (per qh) at keys {st*16 + g*4 + r}

    // ---- softmax: lane-local max/exp/sum, 2 shuffles per qh ----
#pragma unroll
    for (int qh = 0; qh < 2; ++qh) {
      float s0 = sacc[qh][0][0], s1 = sacc[qh][0][1];
      float s2 = sacc[qh][0][2], s3 = sacc[qh][0][3];
      float s4 = sacc[qh][1][0], s5 = sacc[qh][1][1];
      float s6 = sacc[qh][1][2], s7 = sacc[qh][1][3];
      float m8 = fmaxf(fmaxf(fmaxf(s0, s1), fmaxf(s2, s3)),
                       fmaxf(fmaxf(s4, s5), fmaxf(s6, s7)));
      float mt = fmaxf(m8, __shfl_xor(m8, 16));
      mt = fmaxf(mt, __shfl_xor(mt, 32));
      if (__any(mt > m_run[qh] + 8.f)) {  // rare after first tile
        float mn = fmaxf(m_run[qh], mt);
        float f = fexp2(m_run[qh] - mn);
        l_run[qh] *= f;
#pragma unroll
        for (int cst = 0; cst < 8; ++cst) {
          facc[qh][cst][0] *= f; facc[qh][cst][1] *= f;
          facc[qh][cst][2] *= f; facc[qh][cst][3] *= f;
        }
        m_run[qh] = mn;
      }
      float mr = m_run[qh];
      float e0 = fexp2(s0 - mr), e1 = fexp2(s1 - mr);
      float e2 = fexp2(s2 - mr), e3 = fexp2(s3 - mr);
      float e4 = fexp2(s4 - mr), e5 = fexp2(s5 - mr);
      float e6 = fexp2(s6 - mr), e7 = fexp2(s7 - mr);
      l_run[qh] += ((e0 + e1) + (e2 + e3)) + ((e4 + e5) + (e6 + e7));
      u32x2 w0, w1;
      w0[0] = pk2(e0, e1); w0[1] = pk2(e2, e3);   // keys g*4 + 0..3
      w1[0] = pk2(e4, e5); w1[1] = pk2(e6, e7);   // keys 16 + g*4 + 0..3
      unsigned short* pb = Pw + qh * 512 + l15 * 32;
      *reinterpret_cast<u32x2*>(pb + ((g ^ x2) << 2)) = w0;       // granule g
      *reinterpret_cast<u32x2*>(pb + (((4 + g) ^ x2) << 2)) = w1; // granule 4+g
    }

    // ---- PV swapped: facc[qh][cst] += V(A) x P(B) -> D[c][q=l15] ----
    s8b pa[2];
#pragma unroll
    for (int qh = 0; qh < 2; ++qh)
      pa[qh] = *reinterpret_cast<const s8b*>(Pw + qh * 512 + l15 * 32 + ppx * 8);
    __builtin_amdgcn_s_setprio(1);
#pragma unroll
    for (int cst = 0; cst < 8; ++cst) {
      int c = cst * 16 + l15;
      int ck = (h * 4 + g) ^ (c & 7);
      s8b vf = *reinterpret_cast<const s8b*>(&Vs[c * 128 + ck * 8]);
      facc[0][cst] = MFMA16(vf, pa[0], facc[0][cst]);
      facc[1][cst] = MFMA16(vf, pa[1], facc[1][cst]);
    }
    __builtin_amdgcn_s_setprio(0);
  }

  // ---- epilogue: reduce l over the 4 g-replicas, merge 4 key-teams ----
  float l_red[2];
#pragma unroll
  for (int qh = 0; qh < 2; ++qh) {
    float rs = l_run[qh];
    rs += __shfl_xor(rs, 16);
    rs += __shfl_xor(rs, 32);
    l_red[qh] = rs;
  }
  __syncthreads();  // all LDS reads done before overlay

  float* Mb = (float*)smem;            // [4 team][64 row]
  float* Lb = (float*)(smem + 1024);   // [4 team][64 row]
  float* Db = (float*)(smem + 2048);   // [64]
  float* Obuf = (float*)(smem + 4096); // [64][132]

  if (g == 0) {
#pragma unroll
    for (int qh = 0; qh < 2; ++qh) {
      int ra = rhalf * 32 + qh * 16 + l15;
      Mb[h * 64 + ra] = m_run[qh];
      Lb[h * 64 + ra] = l_red[qh];
    }
  }
  __syncthreads();
  float fsc[2];
#pragma unroll
  for (int qh = 0; qh < 2; ++qh) {
    int ra = rhalf * 32 + qh * 16 + l15;
    float M = fmaxf(fmaxf(Mb[ra], Mb[64 + ra]), fmaxf(Mb[128 + ra], Mb[192 + ra]));
    fsc[qh] = fexp2(m_run[qh] - M);
    if (h == 0 && g == 0) {
      float den = Lb[ra] * fexp2(Mb[ra] - M) + Lb[64 + ra] * fexp2(Mb[64 + ra] - M) +
                  Lb[128 + ra] * fexp2(Mb[128 + ra] - M) +
                  Lb[192 + ra] * fexp2(Mb[192 + ra] - M);
      Db[ra] = 1.f / den;
    }
  }
#pragma unroll
  for (int t = 0; t < 4; ++t) {
    __syncthreads();
    if (h == t) {
#pragma unroll
      for (int qh = 0; qh < 2; ++qh) {
        int ra = rhalf * 32 + qh * 16 + l15;
#pragma unroll
        for (int cst = 0; cst < 8; ++cst)
#pragma unroll
          for (int r = 0; r < 4; ++r) {
            int c = cst * 16 + g * 4 + r;
            float v = facc[qh][cst][r] * fsc[qh];
            if (t == 0) Obuf[ra * 132 + c] = v;
            else        Obuf[ra * 132 + c] += v;
          }
      }
    }
  }
  __syncthreads();
#pragma unroll
  for (int it = 0; it < 2; ++it) {
    int idx = it * 512 + tid;  // 1024 = 64 rows x 16 chunks
    int row = idx >> 4;
    int j = idx & 15;
    float inv = Db[row];
    float4 v0 = *reinterpret_cast<const float4*>(&Obuf[row * 132 + j * 8]);
    float4 v1 = *reinterpret_cast<const float4*>(&Obuf[row * 132 + j * 8 + 4]);
    float vv[8] = {v0.x, v0.y, v0.z, v0.w, v1.x, v1.y, v1.z, v1.w};
    us8 hh, ll;
#pragma unroll
    for (int t = 0; t < 8; ++t) {
      float v = vv[t] * inv;
      unsigned short hv = f2bf(v);
      hh[t] = hv;
      ll[t] = f2bf(v - bf2f(hv));
    }
    size_t go = ((size_t)b * NN + n0 + row) * CH + j * 8;
    *reinterpret_cast<us8*>(&Oth[go]) = hh;
    *reinterpret_cast<us8*>(&Otl[go]) = ll;
  }
}

// ---------------------------------------------------------------------------
// out_mfma: unchanged from round 6 (passing).
// ---------------------------------------------------------------------------
__global__ __launch_bounds__(256, 2) void out_mfma(
    const unsigned short* __restrict__ Oth, const unsigned short* __restrict__ Otl,
    const float* __restrict__ wo, const float* __restrict__ bo,
    const float* __restrict__ x, const float* __restrict__ gamma,
    float* __restrict__ y)
{
  __shared__ __align__(16) unsigned char smem[67584];
  unsigned short* Oh = (unsigned short*)smem;
  unsigned short* Ol = (unsigned short*)(smem + 16384);
  float* Obuf = (float*)(smem + 32768);

  const int b = blockIdx.y;
  const int n0 = blockIdx.x * 64;
  const int tid = threadIdx.x;
  const int w = tid >> 6, lane = tid & 63, l15 = lane & 15, g = lane >> 4;
  const int ob = w * 32;

  const unsigned short* OhB = Oth + ((size_t)b * NN + n0) * CH;
  const unsigned short* OlB = Otl + ((size_t)b * NN + n0) * CH;
#pragma unroll
  for (int i = 0; i < 4; ++i) {
    int base = i * 4096 + w * 1024;
    int loff = base + lane * 16;
    int row = loff >> 8;
    int chunk = (loff >> 4) & 15;
    int sk = chunk ^ (row & 7);
    GLOAD16(OhB + (size_t)row * CH + sk * 8, smem + base);
    GLOAD16(OlB + (size_t)row * CH + sk * 8, smem + 16384 + base);
  }

  s8b ah[2][4], al[2][4];
#pragma unroll
  for (int m = 0; m < 2; ++m)
#pragma unroll
    for (int kk = 0; kk < 4; ++kk) {
      int o = ob + m * 16 + l15;
      int c = (kk * 4 + g) * 8;
      float4 w0 = *reinterpret_cast<const float4*>(&wo[o * CH + c]);
      float4 w1 = *reinterpret_cast<const float4*>(&wo[o * CH + c + 4]);
      float wv8[8] = {w0.x, w0.y, w0.z, w0.w, w1.x, w1.y, w1.z, w1.w};
      s8b hh, ll;
#pragma unroll
      for (int t = 0; t < 8; ++t) {
        unsigned short hv = f2bf(wv8[t]);
        hh[t] = (short)hv;
        ll[t] = (short)f2bf(wv8[t] - bf2f(hv));
      }
      ah[m][kk] = hh;
      al[m][kk] = ll;
    }
  const float gm = gamma[0];
  __syncthreads();

  f32x4 acc[2][4];
#pragma unroll
  for (int m = 0; m < 2; ++m)
#pragma unroll
    for (int nst = 0; nst < 4; ++nst)
#pragma unroll
      for (int r = 0; r < 4; ++r) acc[m][nst][r] = 0.f;

#pragma unroll
  for (int kk = 0; kk < 4; ++kk)
#pragma unroll
    for (int nst = 0; nst < 4; ++nst) {
      int n = nst * 16 + l15;
      int ck = (kk * 4 + g) ^ (n & 7);
      s8b bh = *reinterpret_cast<const s8b*>(&Oh[n * 128 + ck * 8]);
      s8b bl = *reinterpret_cast<const s8b*>(&Ol[n * 128 + ck * 8]);
#pragma unroll
      for (int m = 0; m < 2; ++m) {
        acc[m][nst] = MFMA16(ah[m][kk], bh, acc[m][nst]);
        acc[m][nst] = MFMA16(ah[m][kk], bl, acc[m][nst]);
        acc[m][nst] = MFMA16(al[m][kk], bh, acc[m][nst]);
      }
    }
  __syncthreads();

#pragma unroll
  for (int m = 0; m < 2; ++m) {
    float4 b4 = *reinterpret_cast<const float4*>(&bo[ob + m * 16 + g * 4]);
    float bb[4] = {b4.x, b4.y, b4.z, b4.w};
#pragma unroll
    for (int nst = 0; nst < 4; ++nst) {
      int n = nst * 16 + l15;
#pragma unroll
      for (int r = 0; r < 4; ++r) {
        int o = ob + m * 16 + g * 4 + r;
        Obuf[o * 68 + n] = gm * (acc[m][nst][r] + bb[r]);
      }
    }
  }
  __syncthreads();
  const float* Xb = x + (size_t)b * CH * NN;
  float* Yb = y + (size_t)b * CH * NN;
#pragma unroll
  for (int it = 0; it < 8; ++it) {
    int idx = it * 256 + tid;
    int o = idx >> 4;
    int n4 = (idx & 15) * 4;
    float4 v = *reinterpret_cast<const float4*>(&Obuf[o * 68 + n4]);
    float4 rx = *reinterpret_cast<const float4*>(&Xb[(size_t)o * NN + n0 + n4]);
    v.x += rx.x; v.y += rx.y; v.z += rx.z; v.w += rx.w;
    *reinterpret_cast<float4*>(&Yb[(size_t)o * NN + n0 + n4]) = v;
  }
}

// ---------------------------------------------------------------------------
extern "C" void kernel_launch(void* const* d_in, const int* in_sizes, int n_in,
                              void* d_out, int out_size, void* d_ws, size_t ws_size,
                              hipStream_t stream) {
  const float* x     = (const float*)d_in[0];
  const float* wq    = (const float*)d_in[1];
  const float* bq    = (const float*)d_in[2];
  const float* wk    = (const float*)d_in[3];
  const float* bk    = (const float*)d_in[4];
  const float* wv    = (const float*)d_in[5];
  const float* bv    = (const float*)d_in[6];
  const float* wo    = (const float*)d_in[7];
  const float* bo    = (const float*)d_in[8];
  const float* gamma = (const float*)d_in[9];
  float* y = (float*)d_out;

  const size_t per = (size_t)BN * NN * CH;  // 2M bf16 elems = 4MB
  unsigned short* Qt  = (unsigned short*)d_ws;  // [B][N][C] (pre-scaled, log2 dom)
  unsigned short* Kt  = Qt + per;               // [B][N][C]
  unsigned short* Vn  = Kt + per;               // [B][C][N]
  unsigned short* Oth = Vn + per;               // [B][N][C] hi
  unsigned short* Otl = Oth + per;              // [B][N][C] lo

  qkv_fused<<<dim3(NN / 64, BN, 3), 256, 0, stream>>>(x, wq, bq, wk, bk, wv, bv,
                                                      Qt, Kt, Vn);
  flash_attn_v6<<<dim3(64, BN), 512, 0, stream>>>(Qt, Kt, Vn, Oth, Otl);
  out_mfma<<<dim3(NN / 64, BN), 256, 0, stream>>>(Oth, Otl, wo, bo, x, gamma, y);
}